// Round 6
// baseline (434.957 us; speedup 1.0000x reference)
//
#include <hip/hip_runtime.h>
#include <hip/hip_fp16.h>

typedef float v2f __attribute__((ext_vector_type(2)));

static constexpr int T = 512;
static constexpr int B = 4096;

__device__ __forceinline__ float frcp_(float x) { return __builtin_amdgcn_rcpf(x); }
__device__ __forceinline__ float sig_(float x) { return frcp_(1.0f + __expf(-x)); }
__device__ __forceinline__ float tanh_(float x) { return 1.0f - 2.0f * frcp_(1.0f + __expf(2.0f * x)); }

// xor-16 butterfly (within a 32-lane group): BitMode offset = (16<<10)|0x1F
__device__ __forceinline__ float swz16_(float v) {
    return __int_as_float(__builtin_amdgcn_ds_swizzle(__float_as_int(v), 0x401F));
}

// Compiler fence + scheduling barrier. All cross-lane traffic stays within
// one wave; same-wave LDS ops execute in program order in HW, so only
// compiler reordering must be prevented.
#define WAVE_SYNC() do { asm volatile("" ::: "memory"); \
                         __builtin_amdgcn_wave_barrier(); \
                         asm volatile("" ::: "memory"); } while (0)

// ---------------- Kernel 1: layer-0 forward AND backward scans -------------
// tid = [s:3][dir:1][j:4]. Each 16-lane unit owns one (sequence, direction):
// lane j owns gate rows j, 16+j, 32+j (full K=16, no split). h exchanged via
// a 16-float LDS slot per unit. Outputs h-stream as f16 to y0f / y0b.
__global__ void __launch_bounds__(256, 2) k_l0(
    const float* __restrict__ x,      // [B,T]
    const float* __restrict__ Wf, const float* __restrict__ Uf,
    const float* __restrict__ bif, const float* __restrict__ bhf,
    const float* __restrict__ Wb, const float* __restrict__ Ub,
    const float* __restrict__ bib, const float* __restrict__ bhb,
    __half* __restrict__ y0f,         // [T,B,16] f16
    __half* __restrict__ y0b)         // [T,B,16] f16
{
    __shared__ float hbuf[256];
    const int tid = threadIdx.x;
    const int j   = tid & 15;
    const int dir = (tid >> 4) & 1;
    const int s   = tid >> 5;
    const int b   = blockIdx.x * 8 + s;
    float* hb = hbuf + (tid >> 4) * 16;

    const float* Wih = dir ? Wb : Wf;
    const float* Whh = dir ? Ub : Uf;
    const float* bih = dir ? bib : bif;
    const float* bhh = dir ? bhb : bhf;

    v2f wr[8], wz[8], wn[8];
    {
        const v2f* pr = reinterpret_cast<const v2f*>(Whh + j * 16);
        const v2f* pz = reinterpret_cast<const v2f*>(Whh + (16 + j) * 16);
        const v2f* pn = reinterpret_cast<const v2f*>(Whh + (32 + j) * 16);
#pragma unroll
        for (int q = 0; q < 8; ++q) { wr[q] = pr[q]; wz[q] = pz[q]; wn[q] = pn[q]; }
    }
    const float wxr  = Wih[j], wxz = Wih[16 + j], wxn = Wih[32 + j];
    const float br   = bih[j] + bhh[j];
    const float bz   = bih[16 + j] + bhh[16 + j];
    const float bin_ = bih[32 + j];
    const float bhn  = bhh[32 + j];

    const int t0   = dir ? (T - 1) : 0;
    const int step = dir ? -1 : 1;
    const float* xp = x + (size_t)b * T + t0;
    __half* yp = (dir ? y0b : y0f) + ((size_t)t0 * B + b) * 16 + j;
    const int ystep = step * B * 16;

    hb[j] = 0.0f;
    WAVE_SYNC();

    float xv = *xp;
    float hj = 0.0f;
    for (int it = 0; it < T; ++it) {
        const int soff = (it < T - 1) ? step : 0;   // clamped prefetch
        float xn = xp[soff];
        v2f A[8];
#pragma unroll
        for (int q = 0; q < 4; ++q) {
            float4 v = *reinterpret_cast<const float4*>(hb + 4 * q);
            A[2 * q + 0][0] = v.x; A[2 * q + 0][1] = v.y;
            A[2 * q + 1][0] = v.z; A[2 * q + 1][1] = v.w;
        }
        v2f a0 = { fmaf(xv, wxr, br), 0.0f };
        v2f a1 = { fmaf(xv, wxz, bz), 0.0f };
        v2f a2 = { bhn, 0.0f };
#pragma unroll
        for (int q = 0; q < 8; ++q) {
            a0 += wr[q] * A[q];
            a1 += wz[q] * A[q];
            a2 += wn[q] * A[q];
        }
        float ar = a0[0] + a0[1];
        float az = a1[0] + a1[1];
        float hn = a2[0] + a2[1];
        float r = sig_(ar), z = sig_(az);
        float n = tanh_(fmaf(r, hn, fmaf(xv, wxn, bin_)));
        hj = fmaf(z, hj - n, n);            // (1-z)*n + z*h
        *yp = __float2half(hj);
        yp += ystep;
        WAVE_SYNC();                        // keep reads above the write
        hb[j] = hj;
        WAVE_SYNC();                        // write before next-iter reads
        xv = xn; xp += soff;
    }
}

// ---------------- Kernel 2: layer-1 forward scan + backward single step ----
// 32 lanes/seq split-K: lane (j, half) owns rows j,16+j,32+j with ih-cols
// [half*16,+16) and hh-cols [half*8,+8). Inputs [y0f(t); y0b(t)] are staged
// into LDS as f32 (8 lanes per half convert one dword each), prefetched one
// step ahead -> only the h1 roundtrip + hh-dot + butterflies are on the
// critical path. LDS per seq: y[0:32) | h1[32:48).
__global__ void __launch_bounds__(256, 2) k_l1(
    const __half* __restrict__ y0f, const __half* __restrict__ y0b,
    const float* __restrict__ Wih1, const float* __restrict__ Whh1,
    const float* __restrict__ bih1, const float* __restrict__ bhh1,
    const float* __restrict__ Wih1b,
    const float* __restrict__ bih1b, const float* __restrict__ bhh1b,
    float* __restrict__ out)              // [B,32]
{
    __shared__ float lds[8 * 48];
    const int tid  = threadIdx.x;
    const int s    = tid >> 5;
    const int l32  = tid & 31;
    const int j    = l32 & 15;
    const int half = l32 >> 4;
    const int b    = blockIdx.x * 8 + s;
    float* sb = lds + s * 48;

    // L1 ih weights: rows j,16+j,32+j, col slice [half*16, +16)
    v2f w1r[8], w1z[8], w1n[8];
    {
        const v2f* pr = reinterpret_cast<const v2f*>(Wih1 + j * 32 + half * 16);
        const v2f* pz = reinterpret_cast<const v2f*>(Wih1 + (16 + j) * 32 + half * 16);
        const v2f* pn = reinterpret_cast<const v2f*>(Wih1 + (32 + j) * 32 + half * 16);
#pragma unroll
        for (int q = 0; q < 8; ++q) { w1r[q] = pr[q]; w1z[q] = pz[q]; w1n[q] = pn[q]; }
    }
    // L1 hh weights: col slice [half*8, +8)
    v2f u1r[4], u1z[4], u1n[4];
    {
        const v2f* pr = reinterpret_cast<const v2f*>(Whh1 + j * 16 + half * 8);
        const v2f* pz = reinterpret_cast<const v2f*>(Whh1 + (16 + j) * 16 + half * 8);
        const v2f* pn = reinterpret_cast<const v2f*>(Whh1 + (32 + j) * 16 + half * 8);
#pragma unroll
        for (int q = 0; q < 4; ++q) { u1r[q] = pr[q]; u1z[q] = pz[q]; u1n[q] = pn[q]; }
    }
    const float b1r_  = half ? 0.0f : bih1[j] + bhh1[j];
    const float b1z_  = half ? 0.0f : bih1[16 + j] + bhh1[16 + j];
    const float b1in_ = half ? 0.0f : bih1[32 + j];
    const float b1hn_ = half ? 0.0f : bhh1[32 + j];

    // staging pointer: dword j (j<8) of the 8-dword f16 row [t][b][0:16)
    const unsigned* yq =
        reinterpret_cast<const unsigned*>(half ? y0b : y0f) + (size_t)b * 8 + j;

    // init: zero h1, stage y(0)
    if (half == 0) sb[32 + j] = 0.0f;
    if (j < 8) {
        unsigned u = *yq;
        float2 f = __half22float2(*reinterpret_cast<const __half2*>(&u));
        *reinterpret_cast<float2*>(&sb[half * 16 + 2 * j]) = f;
    }
    WAVE_SYNC();

    float h1 = 0.0f;
    v2f Bv[8], C[4];
    for (int it = 0; it < T; ++it) {
        // prefetch y(it+1) (clamped; last iter re-stages y(T-1), harmless)
        const unsigned* ysel = (it < T - 1) ? (yq + (size_t)B * 8) : yq;
        unsigned ust = 0;
        if (j < 8) ust = *ysel;
        yq = ysel;
        // LDS reads: y k-slice + h1 k-slice
#pragma unroll
        for (int q = 0; q < 4; ++q) {
            float4 v = *reinterpret_cast<const float4*>(sb + half * 16 + 4 * q);
            Bv[2 * q + 0][0] = v.x; Bv[2 * q + 0][1] = v.y;
            Bv[2 * q + 1][0] = v.z; Bv[2 * q + 1][1] = v.w;
        }
        {
            float4 v0 = *reinterpret_cast<const float4*>(sb + 32 + half * 8);
            float4 v1 = *reinterpret_cast<const float4*>(sb + 32 + half * 8 + 4);
            C[0][0] = v0.x; C[0][1] = v0.y; C[1][0] = v0.z; C[1][1] = v0.w;
            C[2][0] = v1.x; C[2][1] = v1.y; C[3][0] = v1.z; C[3][1] = v1.w;
        }
        // dots: pre_r / pre_z merged (ih+hh); i_n ih-only; h_n hh-only
        v2f c0 = { b1r_, 0.0f };
        v2f c1 = { b1z_, 0.0f };
        v2f c2 = { b1in_, 0.0f };
        v2f c3 = { b1hn_, 0.0f };
#pragma unroll
        for (int q = 0; q < 8; ++q) {
            c0 += w1r[q] * Bv[q];
            c1 += w1z[q] * Bv[q];
            c2 += w1n[q] * Bv[q];
        }
#pragma unroll
        for (int q = 0; q < 4; ++q) {
            c0 += u1r[q] * C[q];
            c1 += u1z[q] * C[q];
            c3 += u1n[q] * C[q];
        }
        float pr  = c0[0] + c0[1];  pr  += swz16_(pr);
        float pz  = c1[0] + c1[1];  pz  += swz16_(pz);
        float i1n = c2[0] + c2[1];  i1n += swz16_(i1n);
        float hn1 = c3[0] + c3[1];  hn1 += swz16_(hn1);
        float r1 = sig_(pr), z1 = sig_(pz);
        float n1 = tanh_(fmaf(r1, hn1, i1n));
        h1 = fmaf(z1, h1 - n1, n1);
        WAVE_SYNC();                       // reads above the writes
        if (half == 0) sb[32 + j] = h1;
        if (j < 8) {
            float2 f = __half22float2(*reinterpret_cast<const __half2*>(&ust));
            *reinterpret_cast<float2*>(&sb[half * 16 + 2 * j]) = f;
        }
        WAVE_SYNC();                       // writes before next-iter reads
    }

    // ---- L1 backward single step at t=T-1 (h=0); Bv still = y(T-1) slice
    v2f d0 = { half ? 0.0f : bih1b[j] + bhh1b[j], 0.0f };
    v2f d1 = { half ? 0.0f : bih1b[16 + j] + bhh1b[16 + j], 0.0f };
    v2f d2 = { half ? 0.0f : bih1b[32 + j], 0.0f };
    {
        const v2f* qr = reinterpret_cast<const v2f*>(Wih1b + j * 32 + half * 16);
        const v2f* qz = reinterpret_cast<const v2f*>(Wih1b + (16 + j) * 32 + half * 16);
        const v2f* qn = reinterpret_cast<const v2f*>(Wih1b + (32 + j) * 32 + half * 16);
#pragma unroll
        for (int q = 0; q < 8; ++q) {
            d0 += qr[q] * Bv[q];
            d1 += qz[q] * Bv[q];
            d2 += qn[q] * Bv[q];
        }
    }
    float gr = d0[0] + d0[1];  gr += swz16_(gr);
    float gz = d1[0] + d1[1];  gz += swz16_(gz);
    float gi = d2[0] + d2[1];  gi += swz16_(gi);
    float rb = sig_(gr), zb = sig_(gz);
    float nb = tanh_(fmaf(rb, bhh1b[32 + j], gi));
    if (half == 0) {
        out[(size_t)b * 32 + j]      = h1;             // forward h1(T-1)
        out[(size_t)b * 32 + 16 + j] = (1.0f - zb) * nb;
    }
}

extern "C" void kernel_launch(void* const* d_in, const int* in_sizes, int n_in,
                              void* d_out, int out_size, void* d_ws, size_t ws_size,
                              hipStream_t stream) {
    const float* x     = (const float*)d_in[0];
    const float* Wih0f = (const float*)d_in[1];
    const float* Whh0f = (const float*)d_in[2];
    const float* bih0f = (const float*)d_in[3];
    const float* bhh0f = (const float*)d_in[4];
    const float* Wih0b = (const float*)d_in[5];
    const float* Whh0b = (const float*)d_in[6];
    const float* bih0b = (const float*)d_in[7];
    const float* bhh0b = (const float*)d_in[8];
    const float* Wih1f = (const float*)d_in[9];
    const float* Whh1f = (const float*)d_in[10];
    const float* bih1f = (const float*)d_in[11];
    const float* bhh1f = (const float*)d_in[12];
    const float* Wih1b = (const float*)d_in[13];
    const float* bih1b = (const float*)d_in[15];
    const float* bhh1b = (const float*)d_in[16];

    __half* y0f = (__half*)d_ws;                          // [T,B,16] f16 = 64 MiB
    __half* y0b = y0f + (size_t)T * B * 16;               // [T,B,16] f16 = 64 MiB
    float* out = (float*)d_out;

    // K1: 8192 (seq,dir) units, 16 units/block -> 512 blocks.
    hipLaunchKernelGGL(k_l0, dim3(B * 2 / 16), dim3(256), 0, stream,
                       x, Wih0f, Whh0f, bih0f, bhh0f,
                       Wih0b, Whh0b, bih0b, bhh0b, y0f, y0b);
    // K2: 4096 seqs, 8 seqs/block -> 512 blocks.
    hipLaunchKernelGGL(k_l1, dim3(B / 8), dim3(256), 0, stream,
                       y0f, y0b, Wih1f, Whh1f, bih1f, bhh1f,
                       Wih1b, bih1b, bhh1b, out);
}

// Round 7
// 331.221 us; speedup vs baseline: 1.3132x; 1.3132x over previous
//
#include <hip/hip_runtime.h>
#include <hip/hip_fp16.h>

typedef float v2f __attribute__((ext_vector_type(2)));
typedef _Float16 v2h __attribute__((ext_vector_type(2)));

static constexpr int T = 512;
static constexpr int B = 4096;

__device__ __forceinline__ float frcp_(float x) { return __builtin_amdgcn_rcpf(x); }
__device__ __forceinline__ float sig_(float x) { return frcp_(1.0f + __expf(-x)); }
__device__ __forceinline__ float tanh_(float x) { return 1.0f - 2.0f * frcp_(1.0f + __expf(2.0f * x)); }

// xor-16 butterfly (within a 32-lane group): BitMode offset = (16<<10)|0x1F
__device__ __forceinline__ float swz16_(float v) {
    return __int_as_float(__builtin_amdgcn_ds_swizzle(__float_as_int(v), 0x401F));
}

__device__ __forceinline__ v2h as_h2(unsigned u) {
    union { unsigned u; v2h h; } c; c.u = u; return c.h;
}
__device__ __forceinline__ v2f h2f_(unsigned u) {
    float2 f = __half22float2(*reinterpret_cast<const __half2*>(&u));
    v2f r; r[0] = f.x; r[1] = f.y; return r;
}

// Compiler fence + scheduling barrier. All cross-lane traffic stays within
// one wave; same-wave LDS ops execute in program order in HW, so only
// compiler reordering must be prevented.
#define WAVE_SYNC() do { asm volatile("" ::: "memory"); \
                         __builtin_amdgcn_wave_barrier(); \
                         asm volatile("" ::: "memory"); } while (0)

// ---------------- Kernel 1: layer-0 forward AND backward scans -------------
// tid = [s:3][dir:1][j:4]. Each 16-lane unit owns one (sequence, direction):
// lane j owns gate rows j, 16+j, 32+j (full K=16). h exchanged via a
// 16-float LDS slot per unit. 2-deep x prefetch. Output f16 [T,B,16].
__global__ void __launch_bounds__(256, 2) k_l0(
    const float* __restrict__ x,      // [B,T]
    const float* __restrict__ Wf, const float* __restrict__ Uf,
    const float* __restrict__ bif, const float* __restrict__ bhf,
    const float* __restrict__ Wb, const float* __restrict__ Ub,
    const float* __restrict__ bib, const float* __restrict__ bhb,
    __half* __restrict__ y0f,         // [T,B,16] f16
    __half* __restrict__ y0b)         // [T,B,16] f16
{
    __shared__ float hbuf[256];
    const int tid = threadIdx.x;
    const int j   = tid & 15;
    const int dir = (tid >> 4) & 1;
    const int s   = tid >> 5;
    const int b   = blockIdx.x * 8 + s;
    float* hb = hbuf + (tid >> 4) * 16;

    const float* Wih = dir ? Wb : Wf;
    const float* Whh = dir ? Ub : Uf;
    const float* bih = dir ? bib : bif;
    const float* bhh = dir ? bhb : bhf;

    v2f wr[8], wz[8], wn[8];
    {
        const v2f* pr = reinterpret_cast<const v2f*>(Whh + j * 16);
        const v2f* pz = reinterpret_cast<const v2f*>(Whh + (16 + j) * 16);
        const v2f* pn = reinterpret_cast<const v2f*>(Whh + (32 + j) * 16);
#pragma unroll
        for (int q = 0; q < 8; ++q) { wr[q] = pr[q]; wz[q] = pz[q]; wn[q] = pn[q]; }
    }
    const float wxr  = Wih[j], wxz = Wih[16 + j], wxn = Wih[32 + j];
    const float br   = bih[j] + bhh[j];
    const float bz   = bih[16 + j] + bhh[16 + j];
    const float bin_ = bih[32 + j];
    const float bhn  = bhh[32 + j];

    const int t0   = dir ? (T - 1) : 0;
    const int step = dir ? -1 : 1;
    const float* xp = x + (size_t)b * T + t0;
    __half* yp = (dir ? y0b : y0f) + ((size_t)t0 * B + b) * 16 + j;
    const ptrdiff_t ystep = (ptrdiff_t)step * B * 16;

    hb[j] = 0.0f;
    WAVE_SYNC();

    float xv = xp[0];
    float x1 = xp[step];
    const float* xq = xp + 2 * step;   // 2-deep prefetch pointer
    float hj = 0.0f;

    for (int it = 0; it < T; ++it) {
        float x2 = *xq;
        if (it < T - 3) xq += step;
        v2f A[8];
#pragma unroll
        for (int q = 0; q < 4; ++q) {
            float4 v = *reinterpret_cast<const float4*>(hb + 4 * q);
            A[2 * q + 0][0] = v.x; A[2 * q + 0][1] = v.y;
            A[2 * q + 1][0] = v.z; A[2 * q + 1][1] = v.w;
        }
        v2f a0 = { fmaf(xv, wxr, br), 0.0f };
        v2f a1 = { fmaf(xv, wxz, bz), 0.0f };
        v2f a2 = { bhn, 0.0f };
#pragma unroll
        for (int q = 0; q < 8; ++q) {
            a0 += wr[q] * A[q];
            a1 += wz[q] * A[q];
            a2 += wn[q] * A[q];
        }
        float ar = a0[0] + a0[1];
        float az = a1[0] + a1[1];
        float hn = a2[0] + a2[1];
        float r = sig_(ar), z = sig_(az);
        float n = tanh_(fmaf(r, hn, fmaf(xv, wxn, bin_)));
        hj = fmaf(z, hj - n, n);            // (1-z)*n + z*h
        *yp = __float2half(hj);
        yp += ystep;
        WAVE_SYNC();                        // reads above the write
        hb[j] = hj;
        WAVE_SYNC();                        // write before next-iter reads
        xv = x1; x1 = x2;
    }
}

// ---------------- Kernel 2: layer-1 forward scan + backward single step ----
// 32 lanes/seq split-K: lane (j, half) owns rows j,16+j,32+j; ih-cols
// [half*16,+16), hh-cols [half*8,+8). Each lane loads its OWN y half-slice
// (16 f16 = 2 dwordx4, broadcast-coalesced across the 16-lane half-group),
// 2-deep prefetched, fed to v_dot2_f32_f16 against f16-packed ih weights.
// LDS: only h1[16] per seq. Critical path: ds_read h1 -> hh dot -> reduce ->
// nonlin -> ds_write.
__global__ void __launch_bounds__(256, 2) k_l1(
    const __half* __restrict__ y0f, const __half* __restrict__ y0b,
    const float* __restrict__ Wih1, const float* __restrict__ Whh1,
    const float* __restrict__ bih1, const float* __restrict__ bhh1,
    const float* __restrict__ Wih1b,
    const float* __restrict__ bih1b, const float* __restrict__ bhh1b,
    float* __restrict__ out)              // [B,32]
{
    __shared__ float h1s[8 * 16];
    const int tid  = threadIdx.x;
    const int s    = tid >> 5;
    const int l32  = tid & 31;
    const int j    = l32 & 15;
    const int half = l32 >> 4;
    const int b    = blockIdx.x * 8 + s;
    float* hb = h1s + s * 16;

    // f16-packed ih weight slices (rows j, 16+j, 32+j; cols [half*16,+16))
    v2h w1r[8], w1z[8], w1n[8];
    {
        const float* pr = Wih1 + j * 32 + half * 16;
        const float* pz = Wih1 + (16 + j) * 32 + half * 16;
        const float* pn = Wih1 + (32 + j) * 32 + half * 16;
#pragma unroll
        for (int q = 0; q < 8; ++q) {
            w1r[q] = (v2h){ (_Float16)pr[2 * q], (_Float16)pr[2 * q + 1] };
            w1z[q] = (v2h){ (_Float16)pz[2 * q], (_Float16)pz[2 * q + 1] };
            w1n[q] = (v2h){ (_Float16)pn[2 * q], (_Float16)pn[2 * q + 1] };
        }
    }
    // f32 hh weight slices (cols [half*8,+8))
    v2f u1r[4], u1z[4], u1n[4];
    {
        const v2f* pr = reinterpret_cast<const v2f*>(Whh1 + j * 16 + half * 8);
        const v2f* pz = reinterpret_cast<const v2f*>(Whh1 + (16 + j) * 16 + half * 8);
        const v2f* pn = reinterpret_cast<const v2f*>(Whh1 + (32 + j) * 16 + half * 8);
#pragma unroll
        for (int q = 0; q < 4; ++q) { u1r[q] = pr[q]; u1z[q] = pz[q]; u1n[q] = pn[q]; }
    }
    const float b1r_  = half ? 0.0f : bih1[j] + bhh1[j];
    const float b1z_  = half ? 0.0f : bih1[16 + j] + bhh1[16 + j];
    const float b1in_ = half ? 0.0f : bih1[32 + j];
    const float b1hn_ = half ? 0.0f : bhh1[32 + j];

    // y row pointer: row [t][b][0:16) of this half's stream = 2 uint4
    const uint4* ybase =
        reinterpret_cast<const uint4*>(half ? y0b : y0f) + (size_t)b * 2;
    const size_t ystr = (size_t)B * 2;

    if (half == 0) hb[j] = 0.0f;
    WAVE_SYNC();

    uint4 ya0 = ybase[0],    ya1 = ybase[1];        // y(0)
    uint4 yb0 = ybase[ystr], yb1 = ybase[ystr + 1]; // y(1)
    const uint4* yq = ybase + 2 * ystr;             // -> y(2)

    float h1 = 0.0f;
    for (int it = 0; it < T; ++it) {
        // h1(t-1) k-slice (critical read, issues first)
        float4 v0 = *reinterpret_cast<const float4*>(hb + half * 8);
        float4 v1 = *reinterpret_cast<const float4*>(hb + half * 8 + 4);
        // prefetch y(t+2)
        uint4 yc0 = yq[0], yc1 = yq[1];
        if (it < T - 3) yq += ystr;
        // ih dots from registers (off critical path)
        float cr = b1r_, cz = b1z_, ci = b1in_;
        {
            const unsigned uu[8] = { ya0.x, ya0.y, ya0.z, ya0.w,
                                     ya1.x, ya1.y, ya1.z, ya1.w };
#pragma unroll
            for (int q = 0; q < 8; ++q) {
                v2h yh = as_h2(uu[q]);
                cr = __builtin_amdgcn_fdot2(yh, w1r[q], cr, false);
                cz = __builtin_amdgcn_fdot2(yh, w1z[q], cz, false);
                ci = __builtin_amdgcn_fdot2(yh, w1n[q], ci, false);
            }
        }
        // hh dots
        v2f C[4];
        C[0][0] = v0.x; C[0][1] = v0.y; C[1][0] = v0.z; C[1][1] = v0.w;
        C[2][0] = v1.x; C[2][1] = v1.y; C[3][0] = v1.z; C[3][1] = v1.w;
        v2f e0 = { 0.0f, 0.0f }, e1 = { 0.0f, 0.0f }, e2 = { 0.0f, 0.0f };
#pragma unroll
        for (int q = 0; q < 4; ++q) {
            e0 += u1r[q] * C[q];
            e1 += u1z[q] * C[q];
            e2 += u1n[q] * C[q];
        }
        float pr  = cr + e0[0] + e0[1];   pr  += swz16_(pr);
        float pz  = cz + e1[0] + e1[1];   pz  += swz16_(pz);
        float i1n = ci;                   i1n += swz16_(i1n);
        float hn1 = b1hn_ + e2[0] + e2[1]; hn1 += swz16_(hn1);
        float r1 = sig_(pr), z1 = sig_(pz);
        float n1 = tanh_(fmaf(r1, hn1, i1n));
        h1 = fmaf(z1, h1 - n1, n1);
        WAVE_SYNC();                       // reads above the write
        if (half == 0) hb[j] = h1;
        WAVE_SYNC();                       // write before next-iter reads
        ya0 = yb0; ya1 = yb1; yb0 = yc0; yb1 = yc1;
    }

    // ---- L1 backward single step at t=T-1 (h=0); ya = y(T-1) slice.
    v2f Y[8];
    {
        const unsigned uu[8] = { ya0.x, ya0.y, ya0.z, ya0.w,
                                 ya1.x, ya1.y, ya1.z, ya1.w };
#pragma unroll
        for (int q = 0; q < 8; ++q) Y[q] = h2f_(uu[q]);
    }
    const v2f* qr = reinterpret_cast<const v2f*>(Wih1b + j * 32 + half * 16);
    const v2f* qz = reinterpret_cast<const v2f*>(Wih1b + (16 + j) * 32 + half * 16);
    const v2f* qn = reinterpret_cast<const v2f*>(Wih1b + (32 + j) * 32 + half * 16);
    v2f d0 = { half ? 0.0f : bih1b[j] + bhh1b[j], 0.0f };
    v2f d1 = { half ? 0.0f : bih1b[16 + j] + bhh1b[16 + j], 0.0f };
    v2f d2 = { half ? 0.0f : bih1b[32 + j], 0.0f };
#pragma unroll
    for (int q = 0; q < 8; ++q) {
        d0 += qr[q] * Y[q];
        d1 += qz[q] * Y[q];
        d2 += qn[q] * Y[q];
    }
    float gr = d0[0] + d0[1];  gr += swz16_(gr);
    float gz = d1[0] + d1[1];  gz += swz16_(gz);
    float gi = d2[0] + d2[1];  gi += swz16_(gi);
    float rb = sig_(gr), zb = sig_(gz);
    float nb = tanh_(fmaf(rb, bhh1b[32 + j], gi));
    if (half == 0) {
        out[(size_t)b * 32 + j]      = h1;              // forward h1(T-1)
        out[(size_t)b * 32 + 16 + j] = (1.0f - zb) * nb;
    }
}

extern "C" void kernel_launch(void* const* d_in, const int* in_sizes, int n_in,
                              void* d_out, int out_size, void* d_ws, size_t ws_size,
                              hipStream_t stream) {
    const float* x     = (const float*)d_in[0];
    const float* Wih0f = (const float*)d_in[1];
    const float* Whh0f = (const float*)d_in[2];
    const float* bih0f = (const float*)d_in[3];
    const float* bhh0f = (const float*)d_in[4];
    const float* Wih0b = (const float*)d_in[5];
    const float* Whh0b = (const float*)d_in[6];
    const float* bih0b = (const float*)d_in[7];
    const float* bhh0b = (const float*)d_in[8];
    const float* Wih1f = (const float*)d_in[9];
    const float* Whh1f = (const float*)d_in[10];
    const float* bih1f = (const float*)d_in[11];
    const float* bhh1f = (const float*)d_in[12];
    const float* Wih1b = (const float*)d_in[13];
    const float* bih1b = (const float*)d_in[15];
    const float* bhh1b = (const float*)d_in[16];

    __half* y0f = (__half*)d_ws;                   // [T,B,16] f16 = 64 MiB
    __half* y0b = y0f + (size_t)T * B * 16;        // [T,B,16] f16 = 64 MiB
    float* out = (float*)d_out;

    // K1: 8192 (seq,dir) units, 16 units/block -> 512 blocks.
    hipLaunchKernelGGL(k_l0, dim3(B * 2 / 16), dim3(256), 0, stream,
                       x, Wih0f, Whh0f, bih0f, bhh0f,
                       Wih0b, Whh0b, bih0b, bhh0b, y0f, y0b);
    // K2: 4096 seqs, 8 seqs/block -> 512 blocks.
    hipLaunchKernelGGL(k_l1, dim3(B / 8), dim3(256), 0, stream,
                       y0f, y0b, Wih1f, Whh1f, bih1f, bhh1f,
                       Wih1b, bih1b, bhh1b, out);
}

// Round 9
// 287.552 us; speedup vs baseline: 1.5126x; 1.1519x over previous
//
#include <hip/hip_runtime.h>
#include <hip/hip_fp16.h>

typedef float v2f __attribute__((ext_vector_type(2)));
typedef _Float16 h4t __attribute__((ext_vector_type(4)));
typedef _Float16 h8t __attribute__((ext_vector_type(8)));
typedef float f4t __attribute__((ext_vector_type(4)));

static constexpr int T = 512;
static constexpr int B = 4096;

__device__ __forceinline__ float frcp_(float x) { return __builtin_amdgcn_rcpf(x); }
__device__ __forceinline__ float sig_(float x) { return frcp_(1.0f + __expf(-x)); }
__device__ __forceinline__ float tanh_(float x) { return 1.0f - 2.0f * frcp_(1.0f + __expf(2.0f * x)); }

// Compiler fence + scheduling barrier (same-wave LDS ops are in-order in HW).
#define WAVE_SYNC() do { asm volatile("" ::: "memory"); \
                         __builtin_amdgcn_wave_barrier(); \
                         asm volatile("" ::: "memory"); } while (0)

// pack 4 floats -> h4t via two v_cvt_pkrtz (RTZ, fine at these magnitudes)
__device__ __forceinline__ h4t pack4_(float a, float b, float c, float d) {
    auto p0 = __builtin_amdgcn_cvt_pkrtz(a, b);   // __fp16 x2
    auto p1 = __builtin_amdgcn_cvt_pkrtz(c, d);
    union { struct { decltype(p0) a, b; } p; h4t h; } cv;
    cv.p.a = p0; cv.p.b = p1;
    return cv.h;
}

// ---------------- Kernel 1: layer-0 forward AND backward scans -------------
// (unchanged from round 7 — proven)
__global__ void __launch_bounds__(256, 2) k_l0(
    const float* __restrict__ x,      // [B,T]
    const float* __restrict__ Wf, const float* __restrict__ Uf,
    const float* __restrict__ bif, const float* __restrict__ bhf,
    const float* __restrict__ Wb, const float* __restrict__ Ub,
    const float* __restrict__ bib, const float* __restrict__ bhb,
    __half* __restrict__ y0f,         // [T,B,16] f16
    __half* __restrict__ y0b)         // [T,B,16] f16
{
    __shared__ float hbuf[256];
    const int tid = threadIdx.x;
    const int j   = tid & 15;
    const int dir = (tid >> 4) & 1;
    const int s   = tid >> 5;
    const int b   = blockIdx.x * 8 + s;
    float* hb = hbuf + (tid >> 4) * 16;

    const float* Wih = dir ? Wb : Wf;
    const float* Whh = dir ? Ub : Uf;
    const float* bih = dir ? bib : bif;
    const float* bhh = dir ? bhb : bhf;

    v2f wr[8], wz[8], wn[8];
    {
        const v2f* pr = reinterpret_cast<const v2f*>(Whh + j * 16);
        const v2f* pz = reinterpret_cast<const v2f*>(Whh + (16 + j) * 16);
        const v2f* pn = reinterpret_cast<const v2f*>(Whh + (32 + j) * 16);
#pragma unroll
        for (int q = 0; q < 8; ++q) { wr[q] = pr[q]; wz[q] = pz[q]; wn[q] = pn[q]; }
    }
    const float wxr  = Wih[j], wxz = Wih[16 + j], wxn = Wih[32 + j];
    const float br   = bih[j] + bhh[j];
    const float bz   = bih[16 + j] + bhh[16 + j];
    const float bin_ = bih[32 + j];
    const float bhn  = bhh[32 + j];

    const int t0   = dir ? (T - 1) : 0;
    const int step = dir ? -1 : 1;
    const float* xp = x + (size_t)b * T + t0;
    __half* yp = (dir ? y0b : y0f) + ((size_t)t0 * B + b) * 16 + j;
    const ptrdiff_t ystep = (ptrdiff_t)step * B * 16;

    hb[j] = 0.0f;
    WAVE_SYNC();

    float xv = xp[0];
    float x1 = xp[step];
    const float* xq = xp + 2 * step;
    float hj = 0.0f;

    for (int it = 0; it < T; ++it) {
        float x2 = *xq;
        if (it < T - 3) xq += step;
        v2f A[8];
#pragma unroll
        for (int q = 0; q < 4; ++q) {
            float4 v = *reinterpret_cast<const float4*>(hb + 4 * q);
            A[2 * q + 0][0] = v.x; A[2 * q + 0][1] = v.y;
            A[2 * q + 1][0] = v.z; A[2 * q + 1][1] = v.w;
        }
        v2f a0 = { fmaf(xv, wxr, br), 0.0f };
        v2f a1 = { fmaf(xv, wxz, bz), 0.0f };
        v2f a2 = { bhn, 0.0f };
#pragma unroll
        for (int q = 0; q < 8; ++q) {
            a0 += wr[q] * A[q];
            a1 += wz[q] * A[q];
            a2 += wn[q] * A[q];
        }
        float ar = a0[0] + a0[1];
        float az = a1[0] + a1[1];
        float hn = a2[0] + a2[1];
        float r = sig_(ar), z = sig_(az);
        float n = tanh_(fmaf(r, hn, fmaf(xv, wxn, bin_)));
        hj = fmaf(z, hj - n, n);
        *yp = __float2half(hj);
        yp += ystep;
        WAVE_SYNC();
        hb[j] = hj;
        WAVE_SYNC();
        xv = x1; x1 = x2;
    }
}

// ---------------- Kernel 2: layer-1 via MFMA, 16 sequences per wave --------
// gates[48x16] = Wih1[48x32] @ y_cat[32x16]  (3x mfma_f32_16x16x32_f16)
//              + Whh1[48x16] @ h1[16x16]     (3x mfma_f32_16x16x16f16)
// D-layout (row=4g+i, col=c) == B-layout (k=4g+i, col=c) of 16x16x16f16, so
// h1_new -> next-step hh B operand is two in-lane v_cvt_pkrtz. No LDS.
__global__ void __launch_bounds__(64, 1) k_l1m(
    const __half* __restrict__ y0f, const __half* __restrict__ y0b,
    const float* __restrict__ Wih1, const float* __restrict__ Whh1,
    const float* __restrict__ bih1, const float* __restrict__ bhh1,
    const float* __restrict__ Wih1b,
    const float* __restrict__ bih1b, const float* __restrict__ bhh1b,
    float* __restrict__ out)              // [B,32]
{
    const int lane = threadIdx.x & 63;
    const int c = lane & 15;          // seq col (B/D) and weight row (A)
    const int g = lane >> 4;          // k-group / row-group
    const int b = blockIdx.x * 16 + c;

    // ---- A fragments, ih tiles r/z/n: A[m=c][k=8g+e]
    h8t Air, Aiz, Ain;
    {
        const float* pr = Wih1 + (size_t)c * 32 + 8 * g;
        const float* pz = Wih1 + (size_t)(16 + c) * 32 + 8 * g;
        const float* pn = Wih1 + (size_t)(32 + c) * 32 + 8 * g;
#pragma unroll
        for (int e = 0; e < 8; ++e) {
            Air[e] = (_Float16)pr[e];
            Aiz[e] = (_Float16)pz[e];
            Ain[e] = (_Float16)pn[e];
        }
    }
    // ---- A fragments, hh tiles: A[m=c][k=4g+e]
    h4t Ahr, Ahz, Ahn;
    {
        const float* pr = Whh1 + (size_t)c * 16 + 4 * g;
        const float* pz = Whh1 + (size_t)(16 + c) * 16 + 4 * g;
        const float* pn = Whh1 + (size_t)(32 + c) * 16 + 4 * g;
#pragma unroll
        for (int e = 0; e < 4; ++e) {
            Ahr[e] = (_Float16)pr[e];
            Ahz[e] = (_Float16)pz[e];
            Ahn[e] = (_Float16)pn[e];
        }
    }
    // ---- bias C vectors (row = 4g+i)
    f4t Crb, Czb, Cnb, Chn, Z4;
#pragma unroll
    for (int i = 0; i < 4; ++i) {
        const int row = 4 * g + i;
        Crb[i] = bih1[row] + bhh1[row];
        Czb[i] = bih1[16 + row] + bhh1[16 + row];
        Cnb[i] = bih1[32 + row];
        Chn[i] = bhh1[32 + row];
        Z4[i]  = 0.0f;
    }

    // ---- y B-fragment source: lane reads 16B = 8 f16 at k=8g..8g+7
    const __half* ysrc = (g < 2) ? y0f : y0b;
    const uint4* yp = reinterpret_cast<const uint4*>(
        ysrc + (size_t)b * 16 + (size_t)(g & 1) * 8);
    const size_t ystr = (size_t)B * 2;            // uint4 per time step

    uint4 ya  = yp[0];          // y(0)
    uint4 yb4 = yp[ystr];       // y(1)

    float h[4] = {0.0f, 0.0f, 0.0f, 0.0f};
    h4t Bh = {};                // h1(-1) = 0

    for (int it = 0; it < T; ++it) {
        const size_t tn = (it < T - 2) ? (size_t)(it + 2) : (size_t)(T - 1);
        uint4 yc = yp[tn * ystr];                 // prefetch y(t+2)
        h8t By;
        { union { uint4 u; h8t h; } cv; cv.u = ya; By = cv.h; }
        f4t Dr = __builtin_amdgcn_mfma_f32_16x16x32_f16(Air, By, Crb, 0, 0, 0);
        f4t Dz = __builtin_amdgcn_mfma_f32_16x16x32_f16(Aiz, By, Czb, 0, 0, 0);
        f4t Dn = __builtin_amdgcn_mfma_f32_16x16x32_f16(Ain, By, Cnb, 0, 0, 0);
        f4t Er = __builtin_amdgcn_mfma_f32_16x16x16f16(Ahr, Bh, Z4, 0, 0, 0);
        f4t Ez = __builtin_amdgcn_mfma_f32_16x16x16f16(Ahz, Bh, Z4, 0, 0, 0);
        f4t En = __builtin_amdgcn_mfma_f32_16x16x16f16(Ahn, Bh, Chn, 0, 0, 0);
#pragma unroll
        for (int i = 0; i < 4; ++i) {
            float r = sig_(Dr[i] + Er[i]);
            float z = sig_(Dz[i] + Ez[i]);
            float n = tanh_(fmaf(r, En[i], Dn[i]));
            h[i] = fmaf(z, h[i] - n, n);          // (1-z)n + z h
        }
        Bh = pack4_(h[0], h[1], h[2], h[3]);
        ya = yb4; yb4 = yc;
    }

    // ---- forward half of the output: h = h1(T-1), rows 4g+i
#pragma unroll
    for (int i = 0; i < 4; ++i)
        out[(size_t)b * 32 + 4 * g + i] = h[i];

    // ---- L1 backward single step at t=T-1 from h=0; ya = y(T-1)
    h8t Abr, Abz, Abn;
    {
        const float* pr = Wih1b + (size_t)c * 32 + 8 * g;
        const float* pz = Wih1b + (size_t)(16 + c) * 32 + 8 * g;
        const float* pn = Wih1b + (size_t)(32 + c) * 32 + 8 * g;
#pragma unroll
        for (int e = 0; e < 8; ++e) {
            Abr[e] = (_Float16)pr[e];
            Abz[e] = (_Float16)pz[e];
            Abn[e] = (_Float16)pn[e];
        }
    }
    f4t Cbr, Cbz, Cbn;
    float ghn[4];
#pragma unroll
    for (int i = 0; i < 4; ++i) {
        const int row = 4 * g + i;
        Cbr[i] = bih1b[row] + bhh1b[row];
        Cbz[i] = bih1b[16 + row] + bhh1b[16 + row];
        Cbn[i] = bih1b[32 + row];
        ghn[i] = bhh1b[32 + row];
    }
    h8t By;
    { union { uint4 u; h8t h; } cv; cv.u = ya; By = cv.h; }
    f4t Dr = __builtin_amdgcn_mfma_f32_16x16x32_f16(Abr, By, Cbr, 0, 0, 0);
    f4t Dz = __builtin_amdgcn_mfma_f32_16x16x32_f16(Abz, By, Cbz, 0, 0, 0);
    f4t Dn = __builtin_amdgcn_mfma_f32_16x16x32_f16(Abn, By, Cbn, 0, 0, 0);
#pragma unroll
    for (int i = 0; i < 4; ++i) {
        float r = sig_(Dr[i]);
        float z = sig_(Dz[i]);
        float n = tanh_(fmaf(r, ghn[i], Dn[i]));
        out[(size_t)b * 32 + 16 + 4 * g + i] = (1.0f - z) * n;
    }
}

extern "C" void kernel_launch(void* const* d_in, const int* in_sizes, int n_in,
                              void* d_out, int out_size, void* d_ws, size_t ws_size,
                              hipStream_t stream) {
    const float* x     = (const float*)d_in[0];
    const float* Wih0f = (const float*)d_in[1];
    const float* Whh0f = (const float*)d_in[2];
    const float* bih0f = (const float*)d_in[3];
    const float* bhh0f = (const float*)d_in[4];
    const float* Wih0b = (const float*)d_in[5];
    const float* Whh0b = (const float*)d_in[6];
    const float* bih0b = (const float*)d_in[7];
    const float* bhh0b = (const float*)d_in[8];
    const float* Wih1f = (const float*)d_in[9];
    const float* Whh1f = (const float*)d_in[10];
    const float* bih1f = (const float*)d_in[11];
    const float* bhh1f = (const float*)d_in[12];
    const float* Wih1b = (const float*)d_in[13];
    const float* bih1b = (const float*)d_in[15];
    const float* bhh1b = (const float*)d_in[16];

    __half* y0f = (__half*)d_ws;                   // [T,B,16] f16 = 64 MiB
    __half* y0b = y0f + (size_t)T * B * 16;        // [T,B,16] f16 = 64 MiB
    float* out = (float*)d_out;

    // K1: 8192 (seq,dir) units, 16 units/block -> 512 blocks.
    hipLaunchKernelGGL(k_l0, dim3(B * 2 / 16), dim3(256), 0, stream,
                       x, Wih0f, Whh0f, bih0f, bhh0f,
                       Wih0b, Whh0b, bih0b, bhh0b, y0f, y0b);
    // K2: 4096 seqs, 16 per wave, 1 wave per block -> 256 blocks.
    hipLaunchKernelGGL(k_l1m, dim3(B / 16), dim3(64), 0, stream,
                       y0f, y0b, Wih1f, Whh1f, bih1f, bhh1f,
                       Wih1b, bih1b, bhh1b, out);
}